// Round 13
// baseline (111.126 us; speedup 1.0000x reference)
//
#include <hip/hip_runtime.h>
#include <hip/hip_fp16.h>
#include <math.h>

// ConditionalSigKerMMDDiscriminator — x,y,z: (64,33,8) fp32 -> scalar fp32.
//
//   K      = sigker(rbf(x,x))   [symmetric]   1040 wave-items (2 pairs each)
//   L_gen  = sigker(lin(y,y))   [symmetric]   1040 items
//   L_true = sigker(lin(z,z))   [symmetric]   1040 items
//   L_mix  = sigker(lin(y,z))   [full]        2048 items
//   Kinv   = (K+I)^-1;  K*Kinv = I - Kinv  =>  W = Kinv - Kinv^2 (symmetric)
//   out    = sum_ij W[i][j]*(Lg+Lt-2Lm)[i][j]
//
// ONE producer/consumer kernel (spin counters; producers never wait):
//   blocks 0..129   : K items (8 waves x 1 item)  -> fence -> cntK++
//   block  130      : consumer: spin cntK==130 -> GJ (overlaps L gen-2)
//                     -> spin cntL==516 -> fused Kinv^2+Lc trace -> out
//   blocks 131..646 : L items                      -> fence -> cntL++
//
// ws floats: [0]=K [4096]=Lg [8192]=Lt [12288]=Lm [16384]=cntK [16385]=cntL

#define SLEN 33

__device__ __forceinline__ float rl(float v, int lane) {
    return __int_as_float(__builtin_amdgcn_readlane(__float_as_int(v), lane));
}

// ---------------------------------------------------------------------------
// One wave-item: 2 signature-kernel pairs (r6/r11-proven 2x2-block wavefront
// PDE, verbatim; LDS slices are wave-private).
// ---------------------------------------------------------------------------
__device__ __forceinline__ void pde_item(int g, int loc,
                                         const float* __restrict__ x,
                                         const float* __restrict__ y,
                                         const float* __restrict__ z,
                                         float* __restrict__ ws,
                                         float4 (*Xi4)[66],
                                         __half (*incH)[1024]) {
    const int lane = threadIdx.x & 63;
    const int h = lane >> 5;        // which pair in this wave
    const int p = lane & 31;        // block-row / build-column

    int pair = 2 * loc + h, gi, gj;
    if (g == 3) {
        gi = pair >> 6; gj = pair & 63;
    } else {
        float ff = sqrtf(8.0f * (float)pair + 1.0f);
        gi = (int)((ff - 1.0f) * 0.5f);
        while ((gi + 1) * (gi + 2) / 2 <= pair) ++gi;
        while (gi * (gi + 1) / 2 > pair) --gi;
        gj = pair - gi * (gi + 1) / 2;
    }

    const float* Ap = (g == 0) ? x : ((g == 2) ? z : y);
    const float* Bp = (g == 0) ? x : ((g == 1) ? y : z);
    const float4* As = (const float4*)(Ap + gi * (SLEN * 8));
    const float4* Bs = (const float4*)(Bp + gj * (SLEN * 8));

    for (int k = p; k < 66; k += 32) Xi4[h][k] = As[k];
    float4 b0 = Bs[2*p],   b1 = Bs[2*p+1];
    float4 b2 = Bs[2*p+2], b3 = Bs[2*p+3];
    __syncthreads();

    if (g == 0) {
        // RBF: lane p slides down gram columns p and p+1; no gram tile.
        float nprev;
        {
            float4 a0 = Xi4[h][0], a1 = Xi4[h][1];
            float d0=a0.x-b0.x,d1=a0.y-b0.y,d2=a0.z-b0.z,d3=a0.w-b0.w;
            float d4=a1.x-b1.x,d5=a1.y-b1.y,d6=a1.z-b1.z,d7=a1.w-b1.w;
            float da = d0*d0+d1*d1+d2*d2+d3*d3+d4*d4+d5*d5+d6*d6+d7*d7;
            float e0=a0.x-b2.x,e1=a0.y-b2.y,e2=a0.z-b2.z,e3=a0.w-b2.w;
            float e4=a1.x-b3.x,e5=a1.y-b3.y,e6=a1.z-b3.z,e7=a1.w-b3.w;
            float db = e0*e0+e1*e1+e2*e2+e3*e3+e4*e4+e5*e5+e6*e6+e7*e7;
            nprev = __expf(-db) - __expf(-da);
        }
        for (int k = 1; k <= 32; ++k) {
            float4 a0 = Xi4[h][2*k], a1 = Xi4[h][2*k+1];
            float d0=a0.x-b0.x,d1=a0.y-b0.y,d2=a0.z-b0.z,d3=a0.w-b0.w;
            float d4=a1.x-b1.x,d5=a1.y-b1.y,d6=a1.z-b1.z,d7=a1.w-b1.w;
            float da = d0*d0+d1*d1+d2*d2+d3*d3+d4*d4+d5*d5+d6*d6+d7*d7;
            float e0=a0.x-b2.x,e1=a0.y-b2.y,e2=a0.z-b2.z,e3=a0.w-b2.w;
            float e4=a1.x-b3.x,e5=a1.y-b3.y,e6=a1.z-b3.z,e7=a1.w-b3.w;
            float db = e0*e0+e1*e1+e2*e2+e3*e3+e4*e4+e5*e5+e6*e6+e7*e7;
            float diffk = __expf(-db) - __expf(-da);
            incH[h][(k-1)*32 + p] = __float2half(0.25f * (diffk - nprev));
            nprev = diffk;
        }
    } else {
        // Linear: inc[k][p] = dXi[k]·dXj[p] / 4 (rank-1, no gram).
        float e0=b2.x-b0.x, e1=b2.y-b0.y, e2=b2.z-b0.z, e3=b2.w-b0.w;
        float e4=b3.x-b1.x, e5=b3.y-b1.y, e6=b3.z-b1.z, e7=b3.w-b1.w;
        float4 a0 = Xi4[h][0], a1 = Xi4[h][1];
        #pragma unroll 4
        for (int k = 0; k < 32; ++k) {
            float4 a2 = Xi4[h][2*k+2], a3 = Xi4[h][2*k+3];
            float acc = (a2.x-a0.x)*e0 + (a2.y-a0.y)*e1
                      + (a2.z-a0.z)*e2 + (a2.w-a0.w)*e3
                      + (a3.x-a1.x)*e4 + (a3.y-a1.y)*e5
                      + (a3.z-a1.z)*e6 + (a3.w-a1.w)*e7;
            incH[h][k*32 + p] = __float2half(0.25f * acc);
            a0 = a2; a1 = a3;
        }
    }
    __syncthreads();

    // 2x2-block anti-diagonal wavefront (verified rounds 3-12).
    float c01 = 1.0f, c10 = 1.0f, c11 = 1.0f, dcarry = 1.0f;
    const bool isrow0 = (p == 0);
    const __half* incrow = &incH[h][p * 32];
    #pragma unroll 4
    for (int m = 0; m < 63; ++m) {
        float nb10 = __shfl_up(c10, 1);
        float nb11 = __shfl_up(c11, 1);
        int t = m - p;
        float incv = __half2float(incrow[t & 31]);
        float n0 = isrow0 ? 1.0f : nb10;
        float n1 = isrow0 ? 1.0f : nb11;
        bool t0 = (t == 0);
        float w0 = t0 ? 1.0f : c01;
        float w1 = t0 ? 1.0f : c11;
        float d  = t0 ? 1.0f : dcarry;
        float i2 = incv * incv * (1.0f / 12.0f);
        float C1 = 1.0f + 0.5f * incv + i2;
        float C2 = 1.0f - i2;
        float v00 = (w0  + n0 ) * C1 - d   * C2;
        float v01 = (v00 + n1 ) * C1 - n0  * C2;
        float v10 = (v00 + w1 ) * C1 - w0  * C2;
        float v11 = (v10 + v01) * C1 - v00 * C2;
        c01 = v01; c10 = v10; c11 = v11;
        dcarry = n1;
    }

    if (p == 31) {
        float* dst = ws + g * 4096;
        dst[gi * 64 + gj] = c11;
        if (g != 3) dst[gj * 64 + gi] = c11;
    }
}

// ---------------------------------------------------------------------------
// The mono producer/consumer kernel. 647 blocks x 512 threads, 2 blocks/CU.
// ---------------------------------------------------------------------------
__global__ __launch_bounds__(512, 4)
void mono_kernel(const float* __restrict__ x,
                 const float* __restrict__ y,
                 const float* __restrict__ z,
                 float* __restrict__ ws,
                 unsigned int* __restrict__ cnt,   // [0]=K, [1]=L
                 float* __restrict__ out) {
    union U {
        struct { float4 XiS[16][66]; __half incS[16][1024]; } pde;
        float Kls[64 * 65];
    };
    __shared__ U sm;
    __shared__ float prow[2][2][64];
    __shared__ float red[8];

    const int b   = blockIdx.x;
    const int tid = threadIdx.x;
    const int wv  = tid >> 6;           // wave 0..7

    if (b < 130) {
        // ---- K producers: items 0..1039 (g=0) ----
        pde_item(0, b * 8 + wv, x, y, z, ws,
                 &sm.pde.XiS[2 * wv], &sm.pde.incS[2 * wv]);
        __syncthreads();                 // all waves' stores drained
        if (tid == 0) {
            __threadfence();             // release K writes (device scope)
            atomicAdd(&cnt[0], 1u);
        }
    } else if (b > 130) {
        // ---- L producers: item = (b-131)*8 + wv in [0, 4128) ----
        int item = (b - 131) * 8 + wv;
        int g, loc;
        if (item < 1040)      { g = 1; loc = item; }
        else if (item < 2080) { g = 2; loc = item - 1040; }
        else                  { g = 3; loc = item - 2080; }
        pde_item(g, loc, x, y, z, ws,
                 &sm.pde.XiS[2 * wv], &sm.pde.incS[2 * wv]);
        __syncthreads();
        if (tid == 0) {
            __threadfence();             // release L writes
            atomicAdd(&cnt[1], 1u);
        }
    } else {
        // ---- Consumer: GJ of (K+I), then fused trace (r11/r12-proven) ----
        const int c = tid & 63, w = wv;  // thread owns rows 8w+i

        if (tid == 0) {                  // wait for all K producers
            while (atomicAdd(&cnt[0], 0u) < 130u)
                __builtin_amdgcn_s_sleep(2);
        }
        __syncthreads();
        __threadfence();                 // acquire K

        const float* K = ws;
        float m[8];
        #pragma unroll
        for (int i = 0; i < 8; ++i) {
            int r = w * 8 + i;
            m[i] = K[r * 64 + c] + ((r == c) ? 1.0f : 0.0f);
        }
        #pragma unroll 1
        for (int it = 0; it < 8; ++it) {
            #pragma unroll
            for (int j = 0; j < 4; ++j) {
                const int p0 = 8 * it + 2 * j, p1 = p0 + 1;
                const int i0 = 2 * j, i1 = i0 + 1;     // compile-time
                const int buf = j & 1;
                if (w == it) {
                    float x0 = m[i0], x1 = m[i1];
                    // 2x2 pivot block inverse (SPD principal block, det>0)
                    float a  = rl(x0, p0), bq = rl(x0, p1);
                    float cq = rl(x1, p0), dq = rl(x1, p1);
                    float dinv = 1.0f / (a * dq - bq * cq);
                    float P00 =  dq * dinv, P01 = -bq * dinv;
                    float P10 = -cq * dinv, P11 =  a  * dinv;
                    float sp0 = P00 * x0 + P01 * x1;
                    float sp1 = P10 * x0 + P11 * x1;
                    sp0 = (c == p0) ? P00 : ((c == p1) ? P01 : sp0);
                    sp1 = (c == p0) ? P10 : ((c == p1) ? P11 : sp1);
                    m[i0] = sp0; m[i1] = sp1;
                    prow[buf][0][c] = sp0;
                    prow[buf][1][c] = sp1;
                }
                __syncthreads();
                float s0  = prow[buf][0][c],  s1  = prow[buf][1][c];
                float q00 = prow[buf][0][p0], q01 = prow[buf][0][p1];
                float q10 = prow[buf][1][p0], q11 = prow[buf][1][p1];
                #pragma unroll
                for (int i = 0; i < 8; ++i) {
                    bool pivotRow = (w == it) && (i == i0 || i == i1);
                    float f0 = rl(m[i], p0);
                    float f1 = rl(m[i], p1);
                    float nv = m[i] - f0 * s0 - f1 * s1;
                    float wb0 = -(f0 * q00 + f1 * q10);
                    float wb1 = -(f0 * q01 + f1 * q11);
                    nv = (c == p0) ? wb0 : ((c == p1) ? wb1 : nv);
                    if (!pivotRow) m[i] = nv;
                }
            }
        }
        // m[i] = Kinv[w*8+i][c]; stage for the Kinv^2 pass
        #pragma unroll
        for (int i = 0; i < 8; ++i)
            sm.Kls[(w * 8 + i) * 65 + c] = m[i];

        if (tid == 0) {                  // wait for all L producers
            while (atomicAdd(&cnt[1], 0u) < 516u)
                __builtin_amdgcn_s_sleep(2);
        }
        __syncthreads();
        __threadfence();                 // acquire L

        // fused trace: W = Kinv - Kinv^2; out = sum W[r][c]*Lc[r][c]
        const float* Lg = ws + 4096;
        const float* Lt = ws + 8192;
        const float* Lm = ws + 12288;
        float acc[8] = {0,0,0,0,0,0,0,0};
        #pragma unroll 2
        for (int k = 0; k < 64; ++k) {
            float rv = sm.Kls[k * 65 + c];          // Kinv[k][c]
            #pragma unroll
            for (int i = 0; i < 8; ++i)
                acc[i] = fmaf(rl(m[i], k), rv, acc[i]);   // (Kinv^2)[r][c]
        }
        float local = 0.0f;
        #pragma unroll
        for (int i = 0; i < 8; ++i) {
            int r = w * 8 + i;
            float lc = Lg[r * 64 + c] + Lt[r * 64 + c] - 2.0f * Lm[r * 64 + c];
            local += (m[i] - acc[i]) * lc;
        }
        #pragma unroll
        for (int off = 32; off > 0; off >>= 1)
            local += __shfl_down(local, off);
        if (c == 0) red[w] = local;
        __syncthreads();
        if (tid == 0) {
            float v = 0.0f;
            #pragma unroll
            for (int i = 0; i < 8; ++i) v += red[i];
            out[0] = v;
        }
    }
}

extern "C" void kernel_launch(void* const* d_in, const int* in_sizes, int n_in,
                              void* d_out, int out_size, void* d_ws, size_t ws_size,
                              hipStream_t stream) {
    const float* x = (const float*)d_in[0];
    const float* y = (const float*)d_in[1];
    const float* z = (const float*)d_in[2];
    float* out = (float*)d_out;
    float* ws  = (float*)d_ws;
    unsigned int* cnt = (unsigned int*)(ws + 16384);

    hipMemsetAsync(cnt, 0, 2 * sizeof(unsigned int), stream);
    mono_kernel<<<647, 512, 0, stream>>>(x, y, z, ws, cnt, out);
}

// Round 14
// 102.335 us; speedup vs baseline: 1.0859x; 1.0859x over previous
//
#include <hip/hip_runtime.h>
#include <hip/hip_fp16.h>
#include <math.h>

// ConditionalSigKerMMDDiscriminator — x,y,z: (64,33,8) fp32 -> scalar fp32.
//
//   K      = sigker(rbf(x,x))   [symmetric]   1040 wave-items (2 pairs each)
//   L_gen  = sigker(lin(y,y))   [symmetric]   1040 items
//   L_true = sigker(lin(z,z))   [symmetric]   1040 items
//   L_mix  = sigker(lin(y,z))   [full]        2048 items
//   Kinv   = (K+I)^-1;  K*Kinv = I - Kinv  =>  W = Kinv - Kinv^2 (symmetric)
//   out    = sum_ij W[i][j]*(Lg+Lt-2Lm)[i][j]
//
// K1 (pdeK): 2064 x 64-thr blocks — all 1040 K items + first 1024 L items
//            (pdeK is latency-bound at ~1 wave/SIMD; the extra L wave/SIMD
//             rides in the chain bubbles nearly free).
// K2: 389 x 512-thr blocks — block 0 = register GJ of (K+I) (hidden behind
//     L work), writes Kinv + out[0]=0; blocks 1..388 = L items 1024..4127.
// K3: 64-block trace partials, atomicAdd into out (out zeroed by K2).
//
// ws floats: [0]=K [4096]=Lg [8192]=Lt [12288]=Lm [16384]=Kinv

#define SLEN 33

__device__ __forceinline__ float rl(float v, int lane) {
    return __int_as_float(__builtin_amdgcn_readlane(__float_as_int(v), lane));
}

// ---------------------------------------------------------------------------
// One wave-item: 2 signature-kernel pairs (r6/r11-proven 2x2-block wavefront
// PDE, verbatim; LDS slices are wave-private).
// ---------------------------------------------------------------------------
__device__ __forceinline__ void pde_item(int g, int loc,
                                         const float* __restrict__ x,
                                         const float* __restrict__ y,
                                         const float* __restrict__ z,
                                         float* __restrict__ ws,
                                         float4 (*Xi4)[66],
                                         __half (*incH)[1024]) {
    const int lane = threadIdx.x & 63;
    const int h = lane >> 5;        // which pair in this wave
    const int p = lane & 31;        // block-row / build-column

    int pair = 2 * loc + h, gi, gj;
    if (g == 3) {
        gi = pair >> 6; gj = pair & 63;
    } else {
        float ff = sqrtf(8.0f * (float)pair + 1.0f);
        gi = (int)((ff - 1.0f) * 0.5f);
        while ((gi + 1) * (gi + 2) / 2 <= pair) ++gi;
        while (gi * (gi + 1) / 2 > pair) --gi;
        gj = pair - gi * (gi + 1) / 2;
    }

    const float* Ap = (g == 0) ? x : ((g == 2) ? z : y);
    const float* Bp = (g == 0) ? x : ((g == 1) ? y : z);
    const float4* As = (const float4*)(Ap + gi * (SLEN * 8));
    const float4* Bs = (const float4*)(Bp + gj * (SLEN * 8));

    for (int k = p; k < 66; k += 32) Xi4[h][k] = As[k];
    float4 b0 = Bs[2*p],   b1 = Bs[2*p+1];
    float4 b2 = Bs[2*p+2], b3 = Bs[2*p+3];
    __syncthreads();

    if (g == 0) {
        // RBF: lane p slides down gram columns p and p+1; no gram tile.
        float nprev;
        {
            float4 a0 = Xi4[h][0], a1 = Xi4[h][1];
            float d0=a0.x-b0.x,d1=a0.y-b0.y,d2=a0.z-b0.z,d3=a0.w-b0.w;
            float d4=a1.x-b1.x,d5=a1.y-b1.y,d6=a1.z-b1.z,d7=a1.w-b1.w;
            float da = d0*d0+d1*d1+d2*d2+d3*d3+d4*d4+d5*d5+d6*d6+d7*d7;
            float e0=a0.x-b2.x,e1=a0.y-b2.y,e2=a0.z-b2.z,e3=a0.w-b2.w;
            float e4=a1.x-b3.x,e5=a1.y-b3.y,e6=a1.z-b3.z,e7=a1.w-b3.w;
            float db = e0*e0+e1*e1+e2*e2+e3*e3+e4*e4+e5*e5+e6*e6+e7*e7;
            nprev = __expf(-db) - __expf(-da);
        }
        for (int k = 1; k <= 32; ++k) {
            float4 a0 = Xi4[h][2*k], a1 = Xi4[h][2*k+1];
            float d0=a0.x-b0.x,d1=a0.y-b0.y,d2=a0.z-b0.z,d3=a0.w-b0.w;
            float d4=a1.x-b1.x,d5=a1.y-b1.y,d6=a1.z-b1.z,d7=a1.w-b1.w;
            float da = d0*d0+d1*d1+d2*d2+d3*d3+d4*d4+d5*d5+d6*d6+d7*d7;
            float e0=a0.x-b2.x,e1=a0.y-b2.y,e2=a0.z-b2.z,e3=a0.w-b2.w;
            float e4=a1.x-b3.x,e5=a1.y-b3.y,e6=a1.z-b3.z,e7=a1.w-b3.w;
            float db = e0*e0+e1*e1+e2*e2+e3*e3+e4*e4+e5*e5+e6*e6+e7*e7;
            float diffk = __expf(-db) - __expf(-da);
            incH[h][(k-1)*32 + p] = __float2half(0.25f * (diffk - nprev));
            nprev = diffk;
        }
    } else {
        // Linear: inc[k][p] = dXi[k]·dXj[p] / 4 (rank-1, no gram).
        float e0=b2.x-b0.x, e1=b2.y-b0.y, e2=b2.z-b0.z, e3=b2.w-b0.w;
        float e4=b3.x-b1.x, e5=b3.y-b1.y, e6=b3.z-b1.z, e7=b3.w-b1.w;
        float4 a0 = Xi4[h][0], a1 = Xi4[h][1];
        #pragma unroll 4
        for (int k = 0; k < 32; ++k) {
            float4 a2 = Xi4[h][2*k+2], a3 = Xi4[h][2*k+3];
            float acc = (a2.x-a0.x)*e0 + (a2.y-a0.y)*e1
                      + (a2.z-a0.z)*e2 + (a2.w-a0.w)*e3
                      + (a3.x-a1.x)*e4 + (a3.y-a1.y)*e5
                      + (a3.z-a1.z)*e6 + (a3.w-a1.w)*e7;
            incH[h][k*32 + p] = __float2half(0.25f * acc);
            a0 = a2; a1 = a3;
        }
    }
    __syncthreads();

    // 2x2-block anti-diagonal wavefront (verified rounds 3-13).
    float c01 = 1.0f, c10 = 1.0f, c11 = 1.0f, dcarry = 1.0f;
    const bool isrow0 = (p == 0);
    const __half* incrow = &incH[h][p * 32];
    #pragma unroll 4
    for (int m = 0; m < 63; ++m) {
        float nb10 = __shfl_up(c10, 1);
        float nb11 = __shfl_up(c11, 1);
        int t = m - p;
        float incv = __half2float(incrow[t & 31]);
        float n0 = isrow0 ? 1.0f : nb10;
        float n1 = isrow0 ? 1.0f : nb11;
        bool t0 = (t == 0);
        float w0 = t0 ? 1.0f : c01;
        float w1 = t0 ? 1.0f : c11;
        float d  = t0 ? 1.0f : dcarry;
        float i2 = incv * incv * (1.0f / 12.0f);
        float C1 = 1.0f + 0.5f * incv + i2;
        float C2 = 1.0f - i2;
        float v00 = (w0  + n0 ) * C1 - d   * C2;
        float v01 = (v00 + n1 ) * C1 - n0  * C2;
        float v10 = (v00 + w1 ) * C1 - w0  * C2;
        float v11 = (v10 + v01) * C1 - v00 * C2;
        c01 = v01; c10 = v10; c11 = v11;
        dcarry = n1;
    }

    if (p == 31) {
        float* dst = ws + g * 4096;
        dst[gi * 64 + gj] = c11;
        if (g != 3) dst[gj * 64 + gi] = c11;
    }
}

// ---------------------------------------------------------------------------
// K1: 2064 blocks x 64 threads. Blocks 0..1039: K items (g=0).
// Blocks 1040..2063: L items 0..1023 (all g=1, loc<1040) — these ride the
// latency bubbles of the ~1-wave/SIMD K phase nearly free.
// ---------------------------------------------------------------------------
__global__ __launch_bounds__(64, 5)
void pdeK_kernel(const float* __restrict__ x, const float* __restrict__ y,
                 const float* __restrict__ z, float* __restrict__ ws) {
    __shared__ float4 XiS[2][66];
    __shared__ __half incS[2][1024];
    const int b = blockIdx.x;
    if (b < 1040) pde_item(0, b, x, y, z, ws, XiS, incS);
    else          pde_item(1, b - 1040, x, y, z, ws, XiS, incS);
}

// ---------------------------------------------------------------------------
// K2: 389 blocks x 512 threads (~1.5 blocks/CU). Block 0: GJ of (K+I),
// 8 waves, 8 rows/thread (r11-proven 2x2-pivot ping-pong scheme); writes
// Kinv and zeroes out[0] for K3's atomics. Blocks 1..388: L items 1024..4127.
// ---------------------------------------------------------------------------
__global__ __launch_bounds__(512, 4)
void pdeL_gj_kernel(const float* __restrict__ x, const float* __restrict__ y,
                    const float* __restrict__ z, float* __restrict__ ws,
                    float* __restrict__ out) {
    __shared__ float4 XiS[16][66];
    __shared__ __half incS[16][1024];
    __shared__ float prow[2][2][64];

    const int b   = blockIdx.x;
    const int tid = threadIdx.x;
    const int wv  = tid >> 6;           // wave 0..7

    if (b == 0) {
        // ---- Gauss-Jordan inverse of (K+I); thread (w,c) owns rows 8w+i ----
        const int c = tid & 63, w = wv;
        const float* K = ws;
        float* Kinv = ws + 16384;
        float m[8];
        #pragma unroll
        for (int i = 0; i < 8; ++i) {
            int r = w * 8 + i;
            m[i] = K[r * 64 + c] + ((r == c) ? 1.0f : 0.0f);
        }
        #pragma unroll 1
        for (int it = 0; it < 8; ++it) {
            #pragma unroll
            for (int j = 0; j < 4; ++j) {
                const int p0 = 8 * it + 2 * j, p1 = p0 + 1;
                const int i0 = 2 * j, i1 = i0 + 1;     // compile-time
                const int buf = j & 1;
                if (w == it) {
                    float x0 = m[i0], x1 = m[i1];
                    // 2x2 pivot block inverse (SPD principal block, det>0)
                    float a  = rl(x0, p0), bq = rl(x0, p1);
                    float cq = rl(x1, p0), dq = rl(x1, p1);
                    float dinv = 1.0f / (a * dq - bq * cq);
                    float P00 =  dq * dinv, P01 = -bq * dinv;
                    float P10 = -cq * dinv, P11 =  a  * dinv;
                    float sp0 = P00 * x0 + P01 * x1;
                    float sp1 = P10 * x0 + P11 * x1;
                    sp0 = (c == p0) ? P00 : ((c == p1) ? P01 : sp0);
                    sp1 = (c == p0) ? P10 : ((c == p1) ? P11 : sp1);
                    m[i0] = sp0; m[i1] = sp1;
                    prow[buf][0][c] = sp0;
                    prow[buf][1][c] = sp1;
                }
                __syncthreads();
                float s0  = prow[buf][0][c],  s1  = prow[buf][1][c];
                float q00 = prow[buf][0][p0], q01 = prow[buf][0][p1];
                float q10 = prow[buf][1][p0], q11 = prow[buf][1][p1];
                #pragma unroll
                for (int i = 0; i < 8; ++i) {
                    bool pivotRow = (w == it) && (i == i0 || i == i1);
                    float f0 = rl(m[i], p0);
                    float f1 = rl(m[i], p1);
                    float nv = m[i] - f0 * s0 - f1 * s1;
                    float wb0 = -(f0 * q00 + f1 * q10);
                    float wb1 = -(f0 * q01 + f1 * q11);
                    nv = (c == p0) ? wb0 : ((c == p1) ? wb1 : nv);
                    if (!pivotRow) m[i] = nv;
                }
            }
        }
        #pragma unroll
        for (int i = 0; i < 8; ++i)
            Kinv[(w * 8 + i) * 64 + c] = m[i];
        if (tid == 0) out[0] = 0.0f;     // init for K3's atomicAdd
    } else {
        // ---- L items: 1024 + (b-1)*8 + wv in [1024, 4128) ----
        int item = 1024 + (b - 1) * 8 + wv;
        int g, loc;
        if (item < 1040)      { g = 1; loc = item; }
        else if (item < 2080) { g = 2; loc = item - 1040; }
        else                  { g = 3; loc = item - 2080; }
        pde_item(g, loc, x, y, z, ws, &XiS[2 * wv], &incS[2 * wv]);
    }
}

// ---------------------------------------------------------------------------
// K3: block i computes W[i][:] = Kinv[i][:] - (Kinv^2)[i][:], dotted with
// L[:,i] (r3-proven); lane 0 atomicAdds into out (zeroed by K2 block 0).
// ---------------------------------------------------------------------------
__global__ __launch_bounds__(64)
void trace_kernel(const float* __restrict__ ws, float* __restrict__ out) {
    const int i    = blockIdx.x;
    const int lane = threadIdx.x;
    const float* Lg   = ws + 4096;
    const float* Lt   = ws + 8192;
    const float* Lm   = ws + 12288;
    const float* Kinv = ws + 16384;

    float u = Kinv[i * 64 + lane];
    float acc = 0.0f;
    #pragma unroll 8
    for (int k = 0; k < 64; ++k)
        acc = fmaf(__shfl(u, k), Kinv[k * 64 + lane], acc);   // (Kinv^2)[i][lane]
    float wv = u - acc;

    float lc = Lg[lane * 64 + i] + Lt[lane * 64 + i] - 2.0f * Lm[lane * 64 + i];
    float local = wv * lc;
    #pragma unroll
    for (int off = 32; off > 0; off >>= 1)
        local += __shfl_down(local, off);
    if (lane == 0) atomicAdd(out, local);
}

extern "C" void kernel_launch(void* const* d_in, const int* in_sizes, int n_in,
                              void* d_out, int out_size, void* d_ws, size_t ws_size,
                              hipStream_t stream) {
    const float* x = (const float*)d_in[0];
    const float* y = (const float*)d_in[1];
    const float* z = (const float*)d_in[2];
    float* out = (float*)d_out;
    float* ws  = (float*)d_ws;      // 20480 floats = 80 KB used

    pdeK_kernel<<<2064, 64, 0, stream>>>(x, y, z, ws);
    pdeL_gj_kernel<<<389, 512, 0, stream>>>(x, y, z, ws, out);
    trace_kernel<<<64, 64, 0, stream>>>(ws, out);
}

// Round 15
// 99.772 us; speedup vs baseline: 1.1138x; 1.0257x over previous
//
#include <hip/hip_runtime.h>
#include <hip/hip_fp16.h>
#include <math.h>

// ConditionalSigKerMMDDiscriminator — x,y,z: (64,33,8) fp32 -> scalar fp32.
//
//   K      = sigker(rbf(x,x))   [symmetric]   1040 wave-items (2 pairs each)
//   L_gen  = sigker(lin(y,y))   [symmetric]   1040 items
//   L_true = sigker(lin(z,z))   [symmetric]   1040 items
//   L_mix  = sigker(lin(y,z))   [full]        2048 items
//   Kinv   = (K+I)^-1;  K*Kinv = I - Kinv  =>  W = Kinv - Kinv^2 (symmetric)
//   out    = sum_ij W[i][j]*(Lg+Lt-2Lm)[i][j]
//
// K1: pde for K only (1040 x 64-thr blocks, runs alone ~8us).
// K2: 517 x 512-thr blocks (2 blocks/CU, all co-resident):
//     block 0 = register GJ of (K+I), hidden behind L; writes Kinv, out=0.
//     blocks 1..516 = exactly ONE L item per wave (4128 exact — no tail).
// K3: 64-block trace, atomicAdd into out.
//
// ws floats: [0]=K [4096]=Lg [8192]=Lt [12288]=Lm [16384]=Kinv

#define SLEN 33

__device__ __forceinline__ float rl(float v, int lane) {
    return __int_as_float(__builtin_amdgcn_readlane(__float_as_int(v), lane));
}

// ---------------------------------------------------------------------------
// One wave-item: 2 signature-kernel pairs (r6/r11-proven 2x2-block wavefront
// PDE, verbatim; LDS slices are wave-private).
// ---------------------------------------------------------------------------
__device__ __forceinline__ void pde_item(int g, int loc,
                                         const float* __restrict__ x,
                                         const float* __restrict__ y,
                                         const float* __restrict__ z,
                                         float* __restrict__ ws,
                                         float4 (*Xi4)[66],
                                         __half (*incH)[1024]) {
    const int lane = threadIdx.x & 63;
    const int h = lane >> 5;        // which pair in this wave
    const int p = lane & 31;        // block-row / build-column

    int pair = 2 * loc + h, gi, gj;
    if (g == 3) {
        gi = pair >> 6; gj = pair & 63;
    } else {
        float ff = sqrtf(8.0f * (float)pair + 1.0f);
        gi = (int)((ff - 1.0f) * 0.5f);
        while ((gi + 1) * (gi + 2) / 2 <= pair) ++gi;
        while (gi * (gi + 1) / 2 > pair) --gi;
        gj = pair - gi * (gi + 1) / 2;
    }

    const float* Ap = (g == 0) ? x : ((g == 2) ? z : y);
    const float* Bp = (g == 0) ? x : ((g == 1) ? y : z);
    const float4* As = (const float4*)(Ap + gi * (SLEN * 8));
    const float4* Bs = (const float4*)(Bp + gj * (SLEN * 8));

    for (int k = p; k < 66; k += 32) Xi4[h][k] = As[k];
    float4 b0 = Bs[2*p],   b1 = Bs[2*p+1];
    float4 b2 = Bs[2*p+2], b3 = Bs[2*p+3];
    __syncthreads();

    if (g == 0) {
        // RBF: lane p slides down gram columns p and p+1; no gram tile.
        float nprev;
        {
            float4 a0 = Xi4[h][0], a1 = Xi4[h][1];
            float d0=a0.x-b0.x,d1=a0.y-b0.y,d2=a0.z-b0.z,d3=a0.w-b0.w;
            float d4=a1.x-b1.x,d5=a1.y-b1.y,d6=a1.z-b1.z,d7=a1.w-b1.w;
            float da = d0*d0+d1*d1+d2*d2+d3*d3+d4*d4+d5*d5+d6*d6+d7*d7;
            float e0=a0.x-b2.x,e1=a0.y-b2.y,e2=a0.z-b2.z,e3=a0.w-b2.w;
            float e4=a1.x-b3.x,e5=a1.y-b3.y,e6=a1.z-b3.z,e7=a1.w-b3.w;
            float db = e0*e0+e1*e1+e2*e2+e3*e3+e4*e4+e5*e5+e6*e6+e7*e7;
            nprev = __expf(-db) - __expf(-da);
        }
        for (int k = 1; k <= 32; ++k) {
            float4 a0 = Xi4[h][2*k], a1 = Xi4[h][2*k+1];
            float d0=a0.x-b0.x,d1=a0.y-b0.y,d2=a0.z-b0.z,d3=a0.w-b0.w;
            float d4=a1.x-b1.x,d5=a1.y-b1.y,d6=a1.z-b1.z,d7=a1.w-b1.w;
            float da = d0*d0+d1*d1+d2*d2+d3*d3+d4*d4+d5*d5+d6*d6+d7*d7;
            float e0=a0.x-b2.x,e1=a0.y-b2.y,e2=a0.z-b2.z,e3=a0.w-b2.w;
            float e4=a1.x-b3.x,e5=a1.y-b3.y,e6=a1.z-b3.z,e7=a1.w-b3.w;
            float db = e0*e0+e1*e1+e2*e2+e3*e3+e4*e4+e5*e5+e6*e6+e7*e7;
            float diffk = __expf(-db) - __expf(-da);
            incH[h][(k-1)*32 + p] = __float2half(0.25f * (diffk - nprev));
            nprev = diffk;
        }
    } else {
        // Linear: inc[k][p] = dXi[k]·dXj[p] / 4 (rank-1, no gram).
        float e0=b2.x-b0.x, e1=b2.y-b0.y, e2=b2.z-b0.z, e3=b2.w-b0.w;
        float e4=b3.x-b1.x, e5=b3.y-b1.y, e6=b3.z-b1.z, e7=b3.w-b1.w;
        float4 a0 = Xi4[h][0], a1 = Xi4[h][1];
        #pragma unroll 4
        for (int k = 0; k < 32; ++k) {
            float4 a2 = Xi4[h][2*k+2], a3 = Xi4[h][2*k+3];
            float acc = (a2.x-a0.x)*e0 + (a2.y-a0.y)*e1
                      + (a2.z-a0.z)*e2 + (a2.w-a0.w)*e3
                      + (a3.x-a1.x)*e4 + (a3.y-a1.y)*e5
                      + (a3.z-a1.z)*e6 + (a3.w-a1.w)*e7;
            incH[h][k*32 + p] = __float2half(0.25f * acc);
            a0 = a2; a1 = a3;
        }
    }
    __syncthreads();

    // 2x2-block anti-diagonal wavefront (verified rounds 3-14).
    float c01 = 1.0f, c10 = 1.0f, c11 = 1.0f, dcarry = 1.0f;
    const bool isrow0 = (p == 0);
    const __half* incrow = &incH[h][p * 32];
    #pragma unroll 4
    for (int m = 0; m < 63; ++m) {
        float nb10 = __shfl_up(c10, 1);
        float nb11 = __shfl_up(c11, 1);
        int t = m - p;
        float incv = __half2float(incrow[t & 31]);
        float n0 = isrow0 ? 1.0f : nb10;
        float n1 = isrow0 ? 1.0f : nb11;
        bool t0 = (t == 0);
        float w0 = t0 ? 1.0f : c01;
        float w1 = t0 ? 1.0f : c11;
        float d  = t0 ? 1.0f : dcarry;
        float i2 = incv * incv * (1.0f / 12.0f);
        float C1 = 1.0f + 0.5f * incv + i2;
        float C2 = 1.0f - i2;
        float v00 = (w0  + n0 ) * C1 - d   * C2;
        float v01 = (v00 + n1 ) * C1 - n0  * C2;
        float v10 = (v00 + w1 ) * C1 - w0  * C2;
        float v11 = (v10 + v01) * C1 - v00 * C2;
        c01 = v01; c10 = v10; c11 = v11;
        dcarry = n1;
    }

    if (p == 31) {
        float* dst = ws + g * 4096;
        dst[gi * 64 + gj] = c11;
        if (g != 3) dst[gj * 64 + gi] = c11;
    }
}

// ---------------------------------------------------------------------------
// K1: K gram only (g=0). 1040 blocks x 64 threads (r6/r11-proven config).
// ---------------------------------------------------------------------------
__global__ __launch_bounds__(64, 5)
void pdeK_kernel(const float* __restrict__ x, const float* __restrict__ y,
                 const float* __restrict__ z, float* __restrict__ ws) {
    __shared__ float4 XiS[2][66];
    __shared__ __half incS[2][1024];
    pde_item(0, blockIdx.x, x, y, z, ws, XiS, incS);
}

// ---------------------------------------------------------------------------
// K2: 517 blocks x 512 threads (2 blocks/CU, all 517 co-resident).
// Block 0: GJ of (K+I), 8 waves, 8 rows/thread (r11-proven 2x2-pivot
// ping-pong scheme); writes Kinv, zeroes out[0]. Blocks 1..516: exactly one
// L item per wave (4128 items total — no serial tail).
// ---------------------------------------------------------------------------
__global__ __launch_bounds__(512, 4)
void pdeL_gj_kernel(const float* __restrict__ x, const float* __restrict__ y,
                    const float* __restrict__ z, float* __restrict__ ws,
                    float* __restrict__ out) {
    __shared__ float4 XiS[16][66];
    __shared__ __half incS[16][1024];
    __shared__ float prow[2][2][64];

    const int b   = blockIdx.x;
    const int tid = threadIdx.x;
    const int wv  = tid >> 6;           // wave 0..7

    if (b == 0) {
        // ---- Gauss-Jordan inverse of (K+I); thread (w,c) owns rows 8w+i ----
        const int c = tid & 63, w = wv;
        const float* K = ws;
        float* Kinv = ws + 16384;
        float m[8];
        #pragma unroll
        for (int i = 0; i < 8; ++i) {
            int r = w * 8 + i;
            m[i] = K[r * 64 + c] + ((r == c) ? 1.0f : 0.0f);
        }
        #pragma unroll 1
        for (int it = 0; it < 8; ++it) {
            #pragma unroll
            for (int j = 0; j < 4; ++j) {
                const int p0 = 8 * it + 2 * j, p1 = p0 + 1;
                const int i0 = 2 * j, i1 = i0 + 1;     // compile-time
                const int buf = j & 1;
                if (w == it) {
                    float x0 = m[i0], x1 = m[i1];
                    // 2x2 pivot block inverse (SPD principal block, det>0)
                    float a  = rl(x0, p0), bq = rl(x0, p1);
                    float cq = rl(x1, p0), dq = rl(x1, p1);
                    float dinv = 1.0f / (a * dq - bq * cq);
                    float P00 =  dq * dinv, P01 = -bq * dinv;
                    float P10 = -cq * dinv, P11 =  a  * dinv;
                    float sp0 = P00 * x0 + P01 * x1;
                    float sp1 = P10 * x0 + P11 * x1;
                    sp0 = (c == p0) ? P00 : ((c == p1) ? P01 : sp0);
                    sp1 = (c == p0) ? P10 : ((c == p1) ? P11 : sp1);
                    m[i0] = sp0; m[i1] = sp1;
                    prow[buf][0][c] = sp0;
                    prow[buf][1][c] = sp1;
                }
                __syncthreads();
                float s0  = prow[buf][0][c],  s1  = prow[buf][1][c];
                float q00 = prow[buf][0][p0], q01 = prow[buf][0][p1];
                float q10 = prow[buf][1][p0], q11 = prow[buf][1][p1];
                #pragma unroll
                for (int i = 0; i < 8; ++i) {
                    bool pivotRow = (w == it) && (i == i0 || i == i1);
                    float f0 = rl(m[i], p0);
                    float f1 = rl(m[i], p1);
                    float nv = m[i] - f0 * s0 - f1 * s1;
                    float wb0 = -(f0 * q00 + f1 * q10);
                    float wb1 = -(f0 * q01 + f1 * q11);
                    nv = (c == p0) ? wb0 : ((c == p1) ? wb1 : nv);
                    if (!pivotRow) m[i] = nv;
                }
            }
        }
        #pragma unroll
        for (int i = 0; i < 8; ++i)
            Kinv[(w * 8 + i) * 64 + c] = m[i];
        if (tid == 0) out[0] = 0.0f;     // init for K3's atomicAdd
    } else {
        // ---- L items: (b-1)*8 + wv in [0, 4128), exactly one per wave ----
        int item = (b - 1) * 8 + wv;
        int g, loc;
        if (item < 1040)      { g = 1; loc = item; }
        else if (item < 2080) { g = 2; loc = item - 1040; }
        else                  { g = 3; loc = item - 2080; }
        pde_item(g, loc, x, y, z, ws, &XiS[2 * wv], &incS[2 * wv]);
    }
}

// ---------------------------------------------------------------------------
// K3: block i computes W[i][:] = Kinv[i][:] - (Kinv^2)[i][:], dotted with
// L[:,i] (r3-proven); lane 0 atomicAdds into out (zeroed by K2 block 0).
// ---------------------------------------------------------------------------
__global__ __launch_bounds__(64)
void trace_kernel(const float* __restrict__ ws, float* __restrict__ out) {
    const int i    = blockIdx.x;
    const int lane = threadIdx.x;
    const float* Lg   = ws + 4096;
    const float* Lt   = ws + 8192;
    const float* Lm   = ws + 12288;
    const float* Kinv = ws + 16384;

    float u = Kinv[i * 64 + lane];
    float acc = 0.0f;
    #pragma unroll 8
    for (int k = 0; k < 64; ++k)
        acc = fmaf(__shfl(u, k), Kinv[k * 64 + lane], acc);   // (Kinv^2)[i][lane]
    float wv = u - acc;

    float lc = Lg[lane * 64 + i] + Lt[lane * 64 + i] - 2.0f * Lm[lane * 64 + i];
    float local = wv * lc;
    #pragma unroll
    for (int off = 32; off > 0; off >>= 1)
        local += __shfl_down(local, off);
    if (lane == 0) atomicAdd(out, local);
}

extern "C" void kernel_launch(void* const* d_in, const int* in_sizes, int n_in,
                              void* d_out, int out_size, void* d_ws, size_t ws_size,
                              hipStream_t stream) {
    const float* x = (const float*)d_in[0];
    const float* y = (const float*)d_in[1];
    const float* z = (const float*)d_in[2];
    float* out = (float*)d_out;
    float* ws  = (float*)d_ws;      // 20480 floats = 80 KB used

    pdeK_kernel<<<1040, 64, 0, stream>>>(x, y, z, ws);
    pdeL_gj_kernel<<<517, 512, 0, stream>>>(x, y, z, ws, out);
    trace_kernel<<<64, 64, 0, stream>>>(ws, out);
}